// Round 1
// baseline (39596.692 us; speedup 1.0000x reference)
//
#include <hip/hip_runtime.h>
#include <hip/hip_cooperative_groups.h>

namespace cg = cooperative_groups;

typedef _Float16 half8 __attribute__((ext_vector_type(8)));
typedef float floatx4 __attribute__((ext_vector_type(4)));

#define S_LEN 512
#define NB 64
#define NI 256
#define NR 2048
#define K0 (NR + NI)   /* 2304 */
#define K1 (NR + NR)   /* 4096 */
#define LEAK 0.9f

#define GBLK 128
#define TPB 256

// ---- workspace byte offsets ----
#define OFF_W0 ((size_t)0)
#define SZ_W0  ((size_t)NR * K0 * 2)
#define OFF_W1 (OFF_W0 + SZ_W0)
#define SZ_W1  ((size_t)NR * K1 * 2)
#define OFF_XF (OFF_W1 + SZ_W1)
#define SZ_XF  ((size_t)S_LEN * NB * NI * 2)
#define OFF_Y0 (OFF_XF + SZ_XF)
#define SZ_Y0  ((size_t)S_LEN * NB * NR * 2)
#define OFF_H0 (OFF_Y0 + SZ_Y0)
#define SZ_H   ((size_t)2 * NB * NR * 2)   /* ping-pong pair */
#define OFF_H1 (OFF_H0 + SZ_H)

// Convert weights to fp16 concat layout [r][k] with k = [W_hh row | W_in row],
// and x to fp16. One block per output feature r (grid = NR).
__global__ void prep_kernel(const float* __restrict__ x,
                            const float* __restrict__ Win0, const float* __restrict__ Whh0,
                            const float* __restrict__ Win1, const float* __restrict__ Whh1,
                            _Float16* __restrict__ wcat0, _Float16* __restrict__ wcat1,
                            _Float16* __restrict__ xf)
{
    const int r = blockIdx.x;
    for (int k = threadIdx.x; k < K0; k += blockDim.x) {
        float v = (k < NR) ? Whh0[(size_t)r * NR + k] : Win0[(size_t)r * NI + (k - NR)];
        wcat0[(size_t)r * K0 + k] = (_Float16)v;
    }
    for (int k = threadIdx.x; k < K1; k += blockDim.x) {
        float v = (k < NR) ? Whh1[(size_t)r * NR + k] : Win1[(size_t)r * NR + (k - NR)];
        wcat1[(size_t)r * K1 + k] = (_Float16)v;
    }
    const int xchunk = (int)((size_t)S_LEN * NB * NI / NR);  // 4096
    const size_t xbase = (size_t)r * xchunk;
    for (int k = threadIdx.x; k < xchunk; k += blockDim.x)
        xf[xbase + k] = (_Float16)x[xbase + k];
}

// One ESN layer: 512 steps, one grid.sync per step, ping-pong h.
// Each wave computes one 16(batch)x16(feature) tile; fp32 state in registers.
template <int KU>
__device__ __forceinline__ void esn_layer(
    const float* __restrict__ bias_v,
    const _Float16* __restrict__ wcat,   // [NR][NR+KU]
    const _Float16* __restrict__ u,      // [S][NB][KU] fp16 per-step input
    _Float16* __restrict__ hp,           // ping-pong 2*NB*NR fp16 (buf0 zeroed)
    _Float16* __restrict__ yout_f16,     // optional fp16 sequence out
    float* __restrict__ yout_f32,        // optional fp32 sequence out
    float* __restrict__ hn_out,          // final-state out [NB][NR]
    cg::grid_group& grid,
    int m, int ncol, int g, int bj0)
{
    constexpr int KTOT = NR + KU;
    const float bias = bias_v[ncol];
    float hs[4] = {0.f, 0.f, 0.f, 0.f};
    const _Float16* wrow_h = wcat + (size_t)ncol * KTOT + g * 8;
    const _Float16* wrow_u = wrow_h + NR;

    for (int t = 0; t < S_LEN; ++t) {
        const _Float16* hread = hp + (size_t)(t & 1) * (NB * NR) + (size_t)m * NR + g * 8;
        _Float16* hwrite = hp + (size_t)((t + 1) & 1) * (NB * NR);

        floatx4 acc = {bias, bias, bias, bias};
        // recurrent part: K = NR over fp16 h broadcast copy
        #pragma unroll 8
        for (int kb = 0; kb < NR / 32; ++kb) {
            half8 a = *(const half8*)(hread + kb * 32);
            half8 b = *(const half8*)(wrow_h + kb * 32);
            acc = __builtin_amdgcn_mfma_f32_16x16x32_f16(a, b, acc, 0, 0, 0);
        }
        // input part: K = KU
        const _Float16* urow = u + ((size_t)t * NB + m) * KU + g * 8;
        #pragma unroll 8
        for (int kb = 0; kb < KU / 32; ++kb) {
            half8 a = *(const half8*)(urow + kb * 32);
            half8 b = *(const half8*)(wrow_u + kb * 32);
            acc = __builtin_amdgcn_mfma_f32_16x16x32_f16(a, b, acc, 0, 0, 0);
        }
        // leaky integration in exact fp32; publish fp16 copy
        #pragma unroll
        for (int j = 0; j < 4; ++j) {
            float hn = (1.0f - LEAK) * hs[j] + LEAK * tanhf(acc[j]);
            hs[j] = hn;
            const int bj = bj0 + j;
            _Float16 hh = (_Float16)hn;
            hwrite[(size_t)bj * NR + ncol] = hh;
            if (yout_f16) yout_f16[((size_t)t * NB + bj) * NR + ncol] = hh;
            if (yout_f32) yout_f32[((size_t)t * NB + bj) * NR + ncol] = hn;
        }
        grid.sync();
    }
    #pragma unroll
    for (int j = 0; j < 4; ++j)
        hn_out[(size_t)(bj0 + j) * NR + ncol] = hs[j];
}

__global__ void __launch_bounds__(TPB, 1) esn_kernel(
    const float* __restrict__ b0, const float* __restrict__ b1,
    const _Float16* __restrict__ wcat0, const _Float16* __restrict__ wcat1,
    const _Float16* __restrict__ xf, _Float16* __restrict__ y0f,
    _Float16* __restrict__ h0p, _Float16* __restrict__ h1p,
    float* __restrict__ out)
{
    cg::grid_group grid = cg::this_grid();
    const int tid = threadIdx.x;
    const int l = tid & 63;
    const int wid = tid >> 6;        // 0..3: batch tile
    const int l15 = l & 15;
    const int g = l >> 4;            // k-chunk group within wave
    const int m = wid * 16 + l15;    // batch row for A loads
    const int ncol = blockIdx.x * 16 + l15;   // output feature (B col)
    const int bj0 = wid * 16 + g * 4;         // batch row of acc reg 0 (C/D layout)

    float* hn_base = out + (size_t)S_LEN * NB * NR;

    // layer 0: u = x (KU = NI), emit y0 as fp16 staging
    esn_layer<NI>(b0, wcat0, xf, h0p, y0f, nullptr, hn_base,
                  grid, m, ncol, g, bj0);
    // layer 1: u = y0 (KU = NR), emit y1 fp32 straight to d_out
    esn_layer<NR>(b1, wcat1, y0f, h1p, nullptr, out, hn_base + (size_t)NB * NR,
                  grid, m, ncol, g, bj0);
}

extern "C" void kernel_launch(void* const* d_in, const int* in_sizes, int n_in,
                              void* d_out, int out_size, void* d_ws, size_t ws_size,
                              hipStream_t stream) {
    const float* x    = (const float*)d_in[0];
    const float* Win0 = (const float*)d_in[1];
    const float* Whh0 = (const float*)d_in[2];
    const float* b0   = (const float*)d_in[3];
    const float* Win1 = (const float*)d_in[4];
    const float* Whh1 = (const float*)d_in[5];
    const float* b1   = (const float*)d_in[6];

    char* ws = (char*)d_ws;
    _Float16* wcat0 = (_Float16*)(ws + OFF_W0);
    _Float16* wcat1 = (_Float16*)(ws + OFF_W1);
    _Float16* xf    = (_Float16*)(ws + OFF_XF);
    _Float16* y0f   = (_Float16*)(ws + OFF_Y0);
    _Float16* h0p   = (_Float16*)(ws + OFF_H0);
    _Float16* h1p   = (_Float16*)(ws + OFF_H1);
    float* out = (float*)d_out;

    // zero both ping-pong h buffers (initial state) — async, graph-capturable
    hipMemsetAsync(ws + OFF_H0, 0, 2 * SZ_H, stream);

    prep_kernel<<<dim3(NR), dim3(256), 0, stream>>>(x, Win0, Whh0, Win1, Whh1,
                                                    wcat0, wcat1, xf);

    void* args[] = {
        (void*)&b0, (void*)&b1, (void*)&wcat0, (void*)&wcat1,
        (void*)&xf, (void*)&y0f, (void*)&h0p, (void*)&h1p, (void*)&out
    };
    hipLaunchCooperativeKernel((void*)esn_kernel, dim3(GBLK), dim3(TPB),
                               args, 0, stream);
}

// Round 2
// 15871.996 us; speedup vs baseline: 2.4948x; 2.4948x over previous
//
#include <hip/hip_runtime.h>

typedef _Float16 half8 __attribute__((ext_vector_type(8)));
typedef float floatx4 __attribute__((ext_vector_type(4)));

#define S_LEN 512
#define NB 64
#define NI 256
#define NR 2048
#define LEAK 0.9f

#define NBLK 256
#define TPB 256
#define NBNR ((size_t)NB * NR)

// ---- workspace offsets ----
#define OFF_BAR ((size_t)0)                       // 4096 B barrier area
#define OFF_H0  ((size_t)4096)                    // 2 x 64x2048 fp16 ping-pong
#define OFF_H1  (OFF_H0 + 2 * NBNR * 2)
#define OFF_XF  (OFF_H1 + 2 * NBNR * 2)           // x as fp16

// x fp32 -> fp16, 8 elems/thread
__global__ void xconv_kernel(const float* __restrict__ x, _Float16* __restrict__ xf) {
    size_t i = ((size_t)blockIdx.x * TPB + threadIdx.x) * 8;
    const float4 a = *(const float4*)(x + i);
    const float4 b = *(const float4*)(x + i + 4);
    half8 v;
    v[0] = (_Float16)a.x; v[1] = (_Float16)a.y; v[2] = (_Float16)a.z; v[3] = (_Float16)a.w;
    v[4] = (_Float16)b.x; v[5] = (_Float16)b.y; v[6] = (_Float16)b.z; v[7] = (_Float16)b.w;
    *(half8*)(xf + i) = v;
}

// two-level grid barrier: 8 padded group counters (32 blocks each) -> root -> gen
__device__ __forceinline__ void gbar(unsigned* bar) {
    __syncthreads();                       // drains each wave's vmcnt (stores in L2)
    if (threadIdx.x == 0) {
        __threadfence();                   // release: L2 writeback to LLC
        unsigned* cnt  = bar + (blockIdx.x & 7) * 32;   // 128 B apart
        unsigned* root = bar + 256;
        unsigned* gen  = bar + 272;
        unsigned g = __hip_atomic_load(gen, __ATOMIC_RELAXED, __HIP_MEMORY_SCOPE_AGENT);
        bool last = false;
        if (__hip_atomic_fetch_add(cnt, 1u, __ATOMIC_ACQ_REL, __HIP_MEMORY_SCOPE_AGENT) == 31u) {
            __hip_atomic_store(cnt, 0u, __ATOMIC_RELAXED, __HIP_MEMORY_SCOPE_AGENT);
            if (__hip_atomic_fetch_add(root, 1u, __ATOMIC_ACQ_REL, __HIP_MEMORY_SCOPE_AGENT) == 7u) {
                __hip_atomic_store(root, 0u, __ATOMIC_RELAXED, __HIP_MEMORY_SCOPE_AGENT);
                __hip_atomic_store(gen, g + 1u, __ATOMIC_RELEASE, __HIP_MEMORY_SCOPE_AGENT);
                last = true;
            }
        }
        if (!last)
            while (__hip_atomic_load(gen, __ATOMIC_RELAXED, __HIP_MEMORY_SCOPE_AGENT) == g)
                __builtin_amdgcn_s_sleep(1);
        __threadfence();                   // acquire: L1/L2 invalidate
    }
    __syncthreads();
}

// stage 16 rows of concat [W_hh | W_in] fp32 -> fp16 into swizzled LDS
template <int KT, int KUcols>
__device__ void stage_w(_Float16* wsm, const float* __restrict__ Whh,
                        const float* __restrict__ Win, int r0) {
    constexpr int CPR = KT / 8;            // 8-half chunks per row
    for (int c = threadIdx.x; c < 16 * CPR; c += TPB) {
        int f = c / CPR;
        int k0 = (c - f * CPR) * 8;
        const float* src = (k0 < NR) ? Whh + (size_t)(r0 + f) * NR + k0
                                     : Win + (size_t)(r0 + f) * KUcols + (k0 - NR);
        float4 a = *(const float4*)src;
        float4 b = *(const float4*)(src + 4);
        half8 v;
        v[0] = (_Float16)a.x; v[1] = (_Float16)a.y; v[2] = (_Float16)a.z; v[3] = (_Float16)a.w;
        v[4] = (_Float16)b.x; v[5] = (_Float16)b.y; v[6] = (_Float16)b.z; v[7] = (_Float16)b.w;
        int byte = f * (KT * 2) + ((k0 * 2) ^ ((f & 7) << 4));
        *(half8*)((char*)wsm + byte) = v;
    }
}

// one timestep for one wave: 16(batch)x16(feat) tile, K = 2048 (recurrent) + KU (input)
template <int KU>
__device__ __forceinline__ void esn_step(
    const _Float16* __restrict__ hrow,   // &h_prev[m*NR]
    const _Float16* __restrict__ urow,   // &u[t][m*KU]
    const char* __restrict__ wlds, float bias, float* hs,
    _Float16* __restrict__ hwr,          // h_new fp16 ping-pong base
    float* __restrict__ ywr,             // optional fp32 y out base
    float* __restrict__ hnwr,            // optional fp32 final-state base
    int g, int bj0, int ncol, int xorv, int frow)
{
    floatx4 ac0 = {0,0,0,0}, ac1 = {0,0,0,0}, ac2 = {0,0,0,0}, ac3 = {0,0,0,0};
#define MSTEP(AC, KB, BASE, AROW) { \
    half8 a_ = *(const half8*)((AROW) + (KB)*32 + g*8); \
    half8 b_ = *(const half8*)(wlds + frow + ((((BASE) + (KB)*64) + g*16) ^ xorv)); \
    AC = __builtin_amdgcn_mfma_f32_16x16x32_f16(a_, b_, AC, 0, 0, 0); }

    #pragma unroll 4
    for (int q = 0; q < 16; ++q) {        // recurrent: K=2048, 64 chunks, 4 chains
        MSTEP(ac0, q*4+0, 0, hrow)
        MSTEP(ac1, q*4+1, 0, hrow)
        MSTEP(ac2, q*4+2, 0, hrow)
        MSTEP(ac3, q*4+3, 0, hrow)
    }
    #pragma unroll
    for (int q = 0; q < KU / 128; ++q) {  // input part: LDS region starts at byte 4096
        MSTEP(ac0, q*4+0, 4096, urow)
        MSTEP(ac1, q*4+1, 4096, urow)
        MSTEP(ac2, q*4+2, 4096, urow)
        MSTEP(ac3, q*4+3, 4096, urow)
    }
#undef MSTEP
    floatx4 acc = (ac0 + ac1) + (ac2 + ac3);
    #pragma unroll
    for (int j = 0; j < 4; ++j) {
        float hn = (1.0f - LEAK) * hs[j] + LEAK * tanhf(acc[j] + bias);
        hs[j] = hn;
        size_t o = (size_t)(bj0 + j) * NR + ncol;
        hwr[o] = (_Float16)hn;
        if (ywr)  ywr[o]  = hn;
        if (hnwr) hnwr[o] = hn;
    }
}

// blocks 0..127: layer 0 (step s); blocks 128..255: layer 1 (step s-1)
__global__ void __launch_bounds__(TPB, 1) esn_kernel(
    const float* __restrict__ b0v, const float* __restrict__ b1v,
    const float* __restrict__ Whh0, const float* __restrict__ Win0,
    const float* __restrict__ Whh1, const float* __restrict__ Win1,
    const _Float16* __restrict__ xf,
    _Float16* __restrict__ h0p, _Float16* __restrict__ h1p,
    unsigned* __restrict__ bar, float* __restrict__ out)
{
    __shared__ __align__(16) _Float16 wsm[16 * 4096];   // 128 KiB
    const int tid = threadIdx.x;
    const int bid = blockIdx.x;
    const int role = bid >> 7;
    const int r0 = (bid & 127) * 16;
    const int l = tid & 63, wid = tid >> 6, l15 = l & 15, g = l >> 4;
    const int m = wid * 16 + l15;          // batch row for A
    const int ncol = r0 + l15;             // feature (B row / C col)
    const int bj0 = wid * 16 + g * 4;      // batch row of acc[0] (C/D layout, m89)
    const int xorv = (l15 & 7) << 4;

    if (role == 0) stage_w<2304, NI>(wsm, Whh0, Win0, r0);
    else           stage_w<4096, NR>(wsm, Whh1, Win1, r0);
    __syncthreads();

    const float bias = (role ? b1v : b0v)[ncol];
    float hs[4] = {0.f, 0.f, 0.f, 0.f};
    float* hn_base = out + (size_t)S_LEN * NBNR + (size_t)role * NBNR;

    for (int s = 0; s < S_LEN + 1; ++s) {
        if (role == 0) {
            if (s < S_LEN) {
                const int t = s;
                esn_step<NI>(h0p + (size_t)(t & 1) * NBNR + (size_t)m * NR,
                             xf + ((size_t)t * NB + m) * NI,
                             (const char*)wsm, bias, hs,
                             h0p + (size_t)((t + 1) & 1) * NBNR,
                             nullptr,
                             (t == S_LEN - 1) ? hn_base : nullptr,
                             g, bj0, ncol, xorv, l15 * (2304 * 2));
            }
        } else {
            if (s >= 1) {
                const int t = s - 1;
                esn_step<NR>(h1p + (size_t)(t & 1) * NBNR + (size_t)m * NR,
                             h0p + (size_t)(s & 1) * NBNR + (size_t)m * NR,  // y0[t]
                             (const char*)wsm, bias, hs,
                             h1p + (size_t)((t + 1) & 1) * NBNR,
                             out + (size_t)t * NBNR,
                             (t == S_LEN - 1) ? hn_base : nullptr,
                             g, bj0, ncol, xorv, l15 * (4096 * 2));
            }
        }
        if (s < S_LEN) gbar(bar);
    }
}

extern "C" void kernel_launch(void* const* d_in, const int* in_sizes, int n_in,
                              void* d_out, int out_size, void* d_ws, size_t ws_size,
                              hipStream_t stream) {
    const float* x    = (const float*)d_in[0];
    const float* Win0 = (const float*)d_in[1];
    const float* Whh0 = (const float*)d_in[2];
    const float* b0   = (const float*)d_in[3];
    const float* Win1 = (const float*)d_in[4];
    const float* Whh1 = (const float*)d_in[5];
    const float* b1   = (const float*)d_in[6];

    char* ws = (char*)d_ws;
    _Float16* xf  = (_Float16*)(ws + OFF_XF);
    _Float16* h0p = (_Float16*)(ws + OFF_H0);
    _Float16* h1p = (_Float16*)(ws + OFF_H1);
    unsigned* bar = (unsigned*)(ws + OFF_BAR);
    float* out = (float*)d_out;

    // zero barrier + both ping-pong h buffers (everything below OFF_XF)
    hipMemsetAsync(ws, 0, OFF_XF, stream);

    xconv_kernel<<<dim3((S_LEN * NB * NI) / (TPB * 8)), dim3(TPB), 0, stream>>>(x, xf);

    void* args[] = { (void*)&b0, (void*)&b1, (void*)&Whh0, (void*)&Win0,
                     (void*)&Whh1, (void*)&Win1, (void*)&xf, (void*)&h0p,
                     (void*)&h1p, (void*)&bar, (void*)&out };
    hipError_t e = hipLaunchCooperativeKernel((void*)esn_kernel, dim3(NBLK), dim3(TPB),
                                              args, 0, stream);
    if (e != hipSuccess) {
        // fallback: plain launch (256 blocks @ 1/CU are co-resident in practice)
        esn_kernel<<<dim3(NBLK), dim3(TPB), 0, stream>>>(
            b0, b1, Whh0, Win0, Whh1, Win1, xf, h0p, h1p, bar, out);
    }
}

// Round 3
// 14050.870 us; speedup vs baseline: 2.8181x; 1.1296x over previous
//
#include <hip/hip_runtime.h>

typedef _Float16 half8 __attribute__((ext_vector_type(8)));
typedef float floatx4 __attribute__((ext_vector_type(4)));

#define S_LEN 512
#define NB 64
#define NI 256
#define NR 2048
#define LEAK 0.9f

#define NBLK 128
#define TPB 512
#define FPB 32               /* features per block */
#define LBLK 64              /* blocks per layer */
#define NBNR ((size_t)NB * NR)

// ---- workspace offsets ----
#define OFF_BAR ((size_t)0)
#define OFF_H0  ((size_t)4096)
#define OFF_H1  (OFF_H0 + 2 * NBNR * 2)
#define OFF_XF  (OFF_H1 + 2 * NBNR * 2)

// x fp32 -> fp16, 8 elems/thread
__global__ void xconv_kernel(const float* __restrict__ x, _Float16* __restrict__ xf) {
    size_t i = ((size_t)blockIdx.x * 256 + threadIdx.x) * 8;
    const float4 a = *(const float4*)(x + i);
    const float4 b = *(const float4*)(x + i + 4);
    half8 v;
    v[0] = (_Float16)a.x; v[1] = (_Float16)a.y; v[2] = (_Float16)a.z; v[3] = (_Float16)a.w;
    v[4] = (_Float16)b.x; v[5] = (_Float16)b.y; v[6] = (_Float16)b.z; v[7] = (_Float16)b.w;
    *(half8*)(xf + i) = v;
}

__device__ __forceinline__ half8 cvt8(const float* s) {
    float4 p = *(const float4*)s, q = *(const float4*)(s + 4);
    half8 v;
    v[0] = (_Float16)p.x; v[1] = (_Float16)p.y; v[2] = (_Float16)p.z; v[3] = (_Float16)p.w;
    v[4] = (_Float16)q.x; v[5] = (_Float16)q.y; v[6] = (_Float16)q.z; v[7] = (_Float16)q.w;
    return v;
}

// two-level grid barrier: 8 padded group counters (16 blocks each) -> root -> gen
__device__ __forceinline__ void gbar(unsigned* bar) {
    __syncthreads();
    if (threadIdx.x == 0) {
        __threadfence();                   // release: L2 writeback
        unsigned* cnt  = bar + (blockIdx.x & 7) * 32;
        unsigned* root = bar + 256;
        unsigned* gen  = bar + 272;
        unsigned g = __hip_atomic_load(gen, __ATOMIC_RELAXED, __HIP_MEMORY_SCOPE_AGENT);
        bool last = false;
        if (__hip_atomic_fetch_add(cnt, 1u, __ATOMIC_ACQ_REL, __HIP_MEMORY_SCOPE_AGENT) == (NBLK / 8 - 1)) {
            __hip_atomic_store(cnt, 0u, __ATOMIC_RELAXED, __HIP_MEMORY_SCOPE_AGENT);
            if (__hip_atomic_fetch_add(root, 1u, __ATOMIC_ACQ_REL, __HIP_MEMORY_SCOPE_AGENT) == 7u) {
                __hip_atomic_store(root, 0u, __ATOMIC_RELAXED, __HIP_MEMORY_SCOPE_AGENT);
                __hip_atomic_store(gen, g + 1u, __ATOMIC_RELEASE, __HIP_MEMORY_SCOPE_AGENT);
                last = true;
            }
        }
        if (!last)
            while (__hip_atomic_load(gen, __ATOMIC_RELAXED, __HIP_MEMORY_SCOPE_AGENT) == g)
                __builtin_amdgcn_s_sleep(1);
        __threadfence();                   // acquire: cache invalidate
    }
    __syncthreads();
}

// One layer, persistent. 8 waves; wave = K-slice owner (weights in VGPRs).
// Wave computes partials for all 2(fg) x 4(bt) 16x16 tiles over its K-slice.
template <int CH, int KU, int ROLE>
__device__ __forceinline__ void esn_layer_run(
    const float* __restrict__ bias_v,
    const float* __restrict__ Whh, const float* __restrict__ Win,
    const _Float16* __restrict__ xf,   // ROLE 0: input sequence
    _Float16* __restrict__ hp,         // own h ping-pong
    _Float16* __restrict__ h0p,        // ROLE 1: producer (y0) ping-pong
    float* __restrict__ out,
    unsigned* __restrict__ bar,
    float* __restrict__ rsc, int r0)
{
    const int tid = threadIdx.x;
    const int l = tid & 63, wid = tid >> 6, l15 = l & 15, g = l >> 4;

    // ---- load this wave's K-slice of W into registers (once) ----
    half8 bwA[CH], bwB[CH];
    #pragma unroll
    for (int c = 0; c < CH; ++c) {
        const int k0 = (wid * CH + c) * 32 + g * 8;
        const float* s0 = (k0 < NR) ? Whh + (size_t)(r0 + l15) * NR + k0
                                    : Win + (size_t)(r0 + l15) * KU + (k0 - NR);
        const float* s1 = (k0 < NR) ? Whh + (size_t)(r0 + 16 + l15) * NR + k0
                                    : Win + (size_t)(r0 + 16 + l15) * KU + (k0 - NR);
        bwA[c] = cvt8(s0);
        bwB[c] = cvt8(s1);
    }

    // epilogue ownership: wave wid finalizes tile (fg_o, bt_o)
    const int fg_o = wid & 1, bt_o = wid >> 1;
    const int ncol = r0 + fg_o * 16 + l15;
    const int bj0 = bt_o * 16 + g * 4;
    const float bias = bias_v[ncol];
    float hs[4] = {0.f, 0.f, 0.f, 0.f};
    float* hn_base = out + (size_t)S_LEN * NBNR + (size_t)ROLE * NBNR;

    for (int s = 0; s < S_LEN + 1; ++s) {
        const int t = (ROLE == 0) ? s : s - 1;
        const bool active = (ROLE == 0) ? (s < S_LEN) : (s >= 1);
        if (active) {
            const _Float16* hrd = hp + (size_t)(t & 1) * NBNR;
            const _Float16* urd = (ROLE == 0)
                ? xf + (size_t)t * NB * NI
                : h0p + (size_t)((t + 1) & 1) * NBNR;

            floatx4 acc[2][4];
            #pragma unroll
            for (int fg = 0; fg < 2; ++fg)
                #pragma unroll
                for (int bt = 0; bt < 4; ++bt)
                    acc[fg][bt] = (floatx4){0.f, 0.f, 0.f, 0.f};

            #pragma unroll
            for (int c = 0; c < CH; ++c) {
                const int KB32 = (wid * CH + c) * 32;
                const bool isH = (KB32 < NR);
                #pragma unroll
                for (int bt = 0; bt < 4; ++bt) {
                    const int row = bt * 16 + l15;
                    const _Float16* pa = isH
                        ? hrd + (size_t)row * NR + KB32 + g * 8
                        : urd + (size_t)row * KU + (KB32 - NR) + g * 8;
                    half8 a = *(const half8*)pa;
                    acc[0][bt] = __builtin_amdgcn_mfma_f32_16x16x32_f16(a, bwA[c], acc[0][bt], 0, 0, 0);
                    acc[1][bt] = __builtin_amdgcn_mfma_f32_16x16x32_f16(a, bwB[c], acc[1][bt], 0, 0, 0);
                }
            }

            // cross-wave K reduction through LDS (linear per-lane slots)
            #pragma unroll
            for (int fg = 0; fg < 2; ++fg)
                #pragma unroll
                for (int bt = 0; bt < 4; ++bt)
                    *(floatx4*)(rsc + (size_t)((wid * 8 + fg * 4 + bt) * 64 + l) * 4) = acc[fg][bt];
            __syncthreads();

            floatx4 r = {0.f, 0.f, 0.f, 0.f};
            #pragma unroll
            for (int v = 0; v < 8; ++v)
                r += *(const floatx4*)(rsc + (size_t)((v * 8 + fg_o * 4 + bt_o) * 64 + l) * 4);

            _Float16* hwr = hp + (size_t)((t + 1) & 1) * NBNR;
            #pragma unroll
            for (int j = 0; j < 4; ++j) {
                float hn = (1.0f - LEAK) * hs[j] + LEAK * tanhf(r[j] + bias);
                hs[j] = hn;
                size_t o = (size_t)(bj0 + j) * NR + ncol;
                hwr[o] = (_Float16)hn;                         // coherent h publish
                if (ROLE == 1)
                    __builtin_nontemporal_store(hn, out + (size_t)t * NBNR + o);
                if (t == S_LEN - 1)
                    __builtin_nontemporal_store(hn, hn_base + o);
            }
        }
        if (s < S_LEN) gbar(bar);
    }
}

// blocks 0..63: layer 0 (step s); blocks 64..127: layer 1 (step s-1)
__global__ void __launch_bounds__(TPB, 2) esn_kernel(
    const float* __restrict__ b0v, const float* __restrict__ b1v,
    const float* __restrict__ Whh0, const float* __restrict__ Win0,
    const float* __restrict__ Whh1, const float* __restrict__ Win1,
    const _Float16* __restrict__ xf,
    _Float16* __restrict__ h0p, _Float16* __restrict__ h1p,
    unsigned* __restrict__ bar, float* __restrict__ out)
{
    __shared__ __align__(16) float rsc[64 * 64 * 4];   // 64 KiB reduction scratch
    const int bid = blockIdx.x;
    if (bid < LBLK)
        esn_layer_run<(NR + NI) / 32 / 8, NI, 0>(b0v, Whh0, Win0, xf, h0p, nullptr,
                                                 out, bar, rsc, bid * FPB);
    else
        esn_layer_run<(NR + NR) / 32 / 8, NR, 1>(b1v, Whh1, Win1, nullptr, h1p, h0p,
                                                 out, bar, rsc, (bid - LBLK) * FPB);
}

extern "C" void kernel_launch(void* const* d_in, const int* in_sizes, int n_in,
                              void* d_out, int out_size, void* d_ws, size_t ws_size,
                              hipStream_t stream) {
    const float* x    = (const float*)d_in[0];
    const float* Win0 = (const float*)d_in[1];
    const float* Whh0 = (const float*)d_in[2];
    const float* b0   = (const float*)d_in[3];
    const float* Win1 = (const float*)d_in[4];
    const float* Whh1 = (const float*)d_in[5];
    const float* b1   = (const float*)d_in[6];

    char* ws = (char*)d_ws;
    _Float16* xf  = (_Float16*)(ws + OFF_XF);
    _Float16* h0p = (_Float16*)(ws + OFF_H0);
    _Float16* h1p = (_Float16*)(ws + OFF_H1);
    unsigned* bar = (unsigned*)(ws + OFF_BAR);
    float* out = (float*)d_out;

    // zero barrier + both h ping-pong pairs
    hipMemsetAsync(ws, 0, OFF_XF, stream);

    xconv_kernel<<<dim3((S_LEN * NB * NI) / (256 * 8)), dim3(256), 0, stream>>>(x, xf);

    void* args[] = { (void*)&b0, (void*)&b1, (void*)&Whh0, (void*)&Win0,
                     (void*)&Whh1, (void*)&Win1, (void*)&xf, (void*)&h0p,
                     (void*)&h1p, (void*)&bar, (void*)&out };
    hipError_t e = hipLaunchCooperativeKernel((void*)esn_kernel, dim3(NBLK), dim3(TPB),
                                              args, 0, stream);
    if (e != hipSuccess) {
        esn_kernel<<<dim3(NBLK), dim3(TPB), 0, stream>>>(
            b0, b1, Whh0, Win0, Whh1, Win1, xf, h0p, h1p, bar, out);
    }
}